// Round 1
// baseline (4782.711 us; speedup 1.0000x reference)
//
#include <hip/hip_runtime.h>

typedef unsigned short u16;
typedef unsigned int u32;
typedef __attribute__((ext_vector_type(8))) short short8;
typedef __attribute__((ext_vector_type(4))) float float4v;

#define B_SZ 4096
#define T_SZ 32
#define XD 256
#define HD 256
#define ZD 256
#define GD 128
#define YD 2

#define BM 32          // batch rows per block
#define NW 16          // waves per block (1024 threads)

// bf16 weight fragment buffer layout in d_ws (elem offsets) — frag-contiguous:
// addr = base + ((ntile*KT + kt)<<9) + lane*8 + j ; lane=(n&15)|(((k>>3)&3)<<4), j=k&7
#define W1_OFF 0              // [Wr|Wu]  N=512 (32 ntiles), KT=24
#define W2_OFF 393216         // Wh       N=256 (16 ntiles), KT=24
#define W3_OFF 589824         // [Wzp|Wzq] N=512 (32 ntiles), KT=17 (K=544: x,h,y+pad)
#define W4_OFF 868352         // [Wpm|Wps|Wqm|Wqs] N=1024 (64 ntiles), KT=8
#define WG_OFF 1130496        // Wg       N=128 (8 ntiles),  KT=24
#define WTOT   1228800

#define YTOT  (B_SZ*T_SZ*YD)        // 262144
#define KLTOT (B_SZ*T_SZ)           // 131072

#define HST 260    // h32 row stride (floats)
#define UST 264    // u_bf row stride (bf16)

__device__ __forceinline__ u16 f2bf(float f) {
    u32 u = __float_as_uint(f);
    u32 r = (u + 0x7fffu + ((u >> 16) & 1u)) >> 16;
    return (u16)r;
}
__device__ __forceinline__ float bf2f(u16 h) {
    return __uint_as_float(((u32)h) << 16);
}
__device__ __forceinline__ float tanh_f(float x) {
    float e = __expf(2.f * x);
    return 1.f - 2.f / (e + 1.f);
}
__device__ __forceinline__ float sigm_f(float x) {
    return 1.f / (1.f + __expf(-x));
}

// a_ga: 48 tiles (mt*24+kt) of 512 elems, frag-contiguous
__device__ __forceinline__ int aga_off(int r, int k) {
    return (((r >> 4) * 24 + (k >> 5)) << 9) + ((((k >> 3) & 3) * 16 + (r & 15)) << 3) + (k & 7);
}
// a3s: 32 tiles ((pq*2+mt)*8+kt) of 512 elems
__device__ __forceinline__ int a3s_off(int r, int k, int pq) {
    return (((pq * 2 + (r >> 4)) * 8 + (k >> 5)) << 9) + ((((k >> 3) & 3) * 16 + (r & 15)) << 3) + (k & 7);
}

#define MFMA(a, b, c) __builtin_amdgcn_mfma_f32_16x16x32_bf16(a, b, c, 0, 0, 0)

// ---------------------------------------------------------------------------
__global__ void prep_weights(const float* __restrict__ Wr, const float* __restrict__ Wu,
                             const float* __restrict__ Wh, const float* __restrict__ Wzp,
                             const float* __restrict__ Wzq, const float* __restrict__ Wpm,
                             const float* __restrict__ Wps, const float* __restrict__ Wqm,
                             const float* __restrict__ Wqs, const float* __restrict__ Wg,
                             u16* __restrict__ wts)
{
    int o = blockIdx.x * 256 + threadIdx.x;
    if (o >= WTOT) return;
    int mat, w, KT;
    if (o < W2_OFF)      { mat = 0; w = o;          KT = 24; }
    else if (o < W3_OFF) { mat = 1; w = o - W2_OFF; KT = 24; }
    else if (o < W4_OFF) { mat = 2; w = o - W3_OFF; KT = 17; }
    else if (o < WG_OFF) { mat = 3; w = o - W4_OFF; KT = 8;  }
    else                 { mat = 4; w = o - WG_OFF; KT = 24; }
    int nt  = w / (KT * 512);
    int rem = w - nt * (KT * 512);
    int kt  = rem >> 9;
    int q   = rem & 511;
    int lane = q >> 3, j = q & 7;
    int n = (nt << 4) | (lane & 15);
    int k = (kt << 5) + ((lane >> 4) << 3) + j;
    float v = 0.f;
    switch (mat) {
        case 0: v = (n < 256) ? Wr[k * 256 + n] : Wu[k * 256 + (n - 256)]; break;
        case 1: v = Wh[k * 256 + n]; break;
        case 2: v = (n < 256) ? (k < 512 ? Wzp[k * 256 + n] : 0.f)
                              : (k < 514 ? Wzq[k * 256 + (n - 256)] : 0.f); break;
        case 3: { int sel = n >> 8; int nn = n & 255;
                  const float* s = (sel == 0) ? Wpm : (sel == 1) ? Wps : (sel == 2) ? Wqm : Wqs;
                  v = s[k * 256 + nn]; } break;
        default: v = Wg[k * 128 + n]; break;
    }
    wts[o] = f2bf(v);
}

// ---------------------------------------------------------------------------
__global__ __launch_bounds__(1024, 4) void vrnn_all(
    const float* __restrict__ x,   const float* __restrict__ y_ph,
    const int*   __restrict__ Tph, const float* __restrict__ h0,
    const float* __restrict__ z0,  const float* __restrict__ eps,
    const float* __restrict__ br,  const float* __restrict__ bu,
    const float* __restrict__ bh,  const float* __restrict__ bzp,
    const float* __restrict__ bpm, const float* __restrict__ bps,
    const float* __restrict__ bzq, const float* __restrict__ bqm,
    const float* __restrict__ bqs, const float* __restrict__ bg,
    const float* __restrict__ by,  const float* __restrict__ Wy,
    const u16*   __restrict__ wts, float* __restrict__ out)
{
    __shared__ __align__(16) u16   a_ga[48 * 512];   // 49.2 KB  [x|h|z] frag tiles
    __shared__ __align__(16) u16   a3s[32 * 512];    // 32.8 KB  [hzp|hzq] frag tiles
    __shared__ __align__(16) float h32[BM * HST];    // 33.3 KB  fp32 recurrent h
    __shared__ __align__(16) u16   u_bf[BM * UST];   // 16.9 KB
    __shared__ float part[8 * BM * 2];               // 2 KB  y-head partials
    __shared__ float kl_acc[BM];
    __shared__ int   tph_s[BM];

    const int tid  = threadIdx.x;
    const int wv   = tid >> 6;
    const int lane = tid & 63;
    const int quad = lane >> 4;
    const int l15  = lane & 15;
    const int b0   = blockIdx.x * BM;

    // --- per-lane register-resident biases / Wy ---
    const int c10 = wv * 32 + l15;          // stage1 cols (nt=0), +16 for nt=1
    const float bs1_0 = (c10 < 256) ? br[c10] : bu[c10 - 256];
    const float bs1_1 = (c10 + 16 < 256) ? br[c10 + 16] : bu[c10 + 16 - 256];
    const int c2  = wv * 16 + l15;          // stage2 col
    const float bh_r = bh[c2];
    const float bz0 = (c10 < 256) ? bzp[c10] : bzq[c10 - 256];
    const float bz1 = (c10 + 16 < 256) ? bzp[c10 + 16] : bzq[c10 + 16 - 256];
    const int zc  = wv * 16 + l15;          // stage4 col
    const float b4pm = bpm[zc], b4ps = bps[zc], b4qm = bqm[zc], b4qs = bqs[zc];
    const int c5  = (wv >> 1) * 16 + l15;   // stage5 col
    const int mt5 = wv & 1;
    const float bg_r = bg[c5];
    const float wy0 = Wy[c5 * 2], wy1 = Wy[c5 * 2 + 1];
    const float by0 = by[0], by1 = by[1];

    if (tid < BM) tph_s[tid] = Tph[b0 + tid];

    const int xr  = tid >> 5;         // staging row
    const int xcc = (tid & 31) * 8;   // staging col base

    // --- x(t=0) prefetch into registers (nontemporal: keep L2 for weights) ---
    float4v xn0, xn1;
    {
        const float* xp = &x[((size_t)(b0 + xr) * T_SZ + 0) * XD + xcc];
        xn0 = __builtin_nontemporal_load((const float4v*)xp);
        xn1 = __builtin_nontemporal_load((const float4v*)(xp + 4));
    }

    // --- init h, z state (vectorized, nontemporal) ---
    {
        const float* hp = &h0[(b0 + xr) * HD + xcc];
        const float* zp = &z0[(b0 + xr) * ZD + xcc];
        float4v ha = __builtin_nontemporal_load((const float4v*)hp);
        float4v hb = __builtin_nontemporal_load((const float4v*)(hp + 4));
        float4v za = __builtin_nontemporal_load((const float4v*)zp);
        float4v zb = __builtin_nontemporal_load((const float4v*)(zp + 4));
        short8 hv, zv;
#pragma unroll
        for (int j = 0; j < 4; ++j) {
            h32[xr * HST + xcc + j]     = ha[j];
            h32[xr * HST + xcc + 4 + j] = hb[j];
            hv[j]     = (short)f2bf(ha[j]);
            hv[4 + j] = (short)f2bf(hb[j]);
            zv[j]     = (short)f2bf(za[j]);
            zv[4 + j] = (short)f2bf(zb[j]);
        }
        *(short8*)&a_ga[aga_off(xr, 256 + xcc)] = hv;
        *(short8*)&a_ga[aga_off(xr, 512 + xcc)] = zv;
    }
    __syncthreads();

    const float4v zero4 = {0.f, 0.f, 0.f, 0.f};

    for (int t = 0; t < T_SZ; ++t) {
        // --- stage x_t into a_ga cols [0,256) from prefetched registers ---
        {
            short8 xv;
#pragma unroll
            for (int j = 0; j < 4; ++j) {
                xv[j]     = (short)f2bf(xn0[j]);
                xv[4 + j] = (short)f2bf(xn1[j]);
            }
            *(short8*)&a_ga[aga_off(xr, xcc)] = xv;
        }
        __syncthreads();   // bar1

        // ============ stage 1: [r|u] = sigmoid([x,h,z] @ W1) ============
        {
            const u16* pB0 = wts + W1_OFF + (((wv * 2    ) * 24) << 9) + lane * 8;
            const u16* pB1 = wts + W1_OFF + (((wv * 2 + 1) * 24) << 9) + lane * 8;
            short8 b0r[4], b1r[4];
#pragma unroll
            for (int p = 0; p < 4; ++p) {
                b0r[p] = *(const short8*)(pB0 + (p << 9));
                b1r[p] = *(const short8*)(pB1 + (p << 9));
            }
            float4v a00 = zero4, a01 = zero4, a10 = zero4, a11 = zero4;
#pragma unroll
            for (int kt = 0; kt < 24; ++kt) {
                short8 aF0 = *(const short8*)&a_ga[(kt << 9) + lane * 8];
                short8 aF1 = *(const short8*)&a_ga[((24 + kt) << 9) + lane * 8];
                short8 bc0 = b0r[kt & 3];
                short8 bc1 = b1r[kt & 3];
                if (kt + 4 < 24) {
                    b0r[kt & 3] = *(const short8*)(pB0 + ((kt + 4) << 9));
                    b1r[kt & 3] = *(const short8*)(pB1 + ((kt + 4) << 9));
                }
                a00 = MFMA(aF0, bc0, a00); a01 = MFMA(aF0, bc1, a01);
                a10 = MFMA(aF1, bc0, a10); a11 = MFMA(aF1, bc1, a11);
            }
            __syncthreads();   // bar2: all a_ga reads done before rh overwrite
#pragma unroll
            for (int mt = 0; mt < 2; ++mt) {
                const float4v* am = (mt == 0) ? &a00 : &a10;
                const float4v* an = (mt == 0) ? &a01 : &a11;
#pragma unroll
                for (int i = 0; i < 4; ++i) {
                    int row = mt * 16 + quad * 4 + i;
                    // nt = 0
                    {
                        int c = c10;
                        float v = (*am)[i];
                        if (c < 256) {
                            float rr = sigm_f(v + bs1_0);
                            a_ga[aga_off(row, 256 + c)] = f2bf(rr * h32[row * HST + c]);
                        } else {
                            u_bf[row * UST + (c - 256)] = f2bf(sigm_f(v + bs1_0));
                        }
                    }
                    // nt = 1
                    {
                        int c = c10 + 16;
                        float v = (*an)[i];
                        if (c < 256) {
                            float rr = sigm_f(v + bs1_1);
                            a_ga[aga_off(row, 256 + c)] = f2bf(rr * h32[row * HST + c]);
                        } else {
                            u_bf[row * UST + (c - 256)] = f2bf(sigm_f(v + bs1_1));
                        }
                    }
                }
            }
            __syncthreads();   // bar3
        }

        // ============ stage 2: h_tilde = tanh([x,rh,z] @ Wh); h update ============
        {
            const u16* pB = wts + W2_OFF + ((wv * 24) << 9) + lane * 8;
            short8 bcr[4];
#pragma unroll
            for (int p = 0; p < 4; ++p)
                bcr[p] = *(const short8*)(pB + (p << 9));
            float4v a0 = zero4, a1 = zero4;
#pragma unroll
            for (int kt = 0; kt < 24; ++kt) {
                short8 aF0 = *(const short8*)&a_ga[(kt << 9) + lane * 8];
                short8 aF1 = *(const short8*)&a_ga[((24 + kt) << 9) + lane * 8];
                short8 bc = bcr[kt & 3];
                if (kt + 4 < 24)
                    bcr[kt & 3] = *(const short8*)(pB + ((kt + 4) << 9));
                a0 = MFMA(aF0, bc, a0);
                a1 = MFMA(aF1, bc, a1);
            }
            __syncthreads();   // bar4: a_ga reads done before h / y writes
#pragma unroll
            for (int mt = 0; mt < 2; ++mt) {
                const float4v* am = (mt == 0) ? &a0 : &a1;
#pragma unroll
                for (int i = 0; i < 4; ++i) {
                    int row = mt * 16 + quad * 4 + i;
                    float ht = tanh_f((*am)[i] + bh_r);
                    float uu = bf2f(u_bf[row * UST + c2]);
                    float hp = h32[row * HST + c2];
                    float h  = (1.f - uu) * hp + uu * ht;
                    h32[row * HST + c2] = h;
                    a_ga[aga_off(row, 256 + c2)] = f2bf(h);
                }
            }
            // y_t + zeros into cols [512,544) (tile kt=16)
            if (tid < 128) {
                int r = tid >> 2, grp = tid & 3;
                short8 v = {0, 0, 0, 0, 0, 0, 0, 0};
                if (grp == 0) {
                    const float* yp = &y_ph[((size_t)(b0 + r) * T_SZ + t) * YD];
                    v[0] = (short)f2bf(__builtin_nontemporal_load(yp));
                    v[1] = (short)f2bf(__builtin_nontemporal_load(yp + 1));
                }
                *(short8*)&a_ga[aga_off(r, 512 + grp * 8)] = v;
            }
            __syncthreads();   // bar5
        }

        // ============ stage 3: [hzp|hzq] = tanh([x,h,y] @ W3) ============
        float er[2][4];        // eps prefetch (consumed in stage 4 epilogue)
        {
#pragma unroll
            for (int mt = 0; mt < 2; ++mt)
#pragma unroll
                for (int i = 0; i < 4; ++i) {
                    int row = mt * 16 + quad * 4 + i;
                    er[mt][i] = __builtin_nontemporal_load(
                        &eps[((size_t)t * B_SZ + (b0 + row)) * ZD + zc]);
                }

            const u16* pB0 = wts + W3_OFF + (((wv * 2    ) * 17) << 9) + lane * 8;
            const u16* pB1 = wts + W3_OFF + (((wv * 2 + 1) * 17) << 9) + lane * 8;
            short8 b0r[4], b1r[4];
#pragma unroll
            for (int p = 0; p < 4; ++p) {
                b0r[p] = *(const short8*)(pB0 + (p << 9));
                b1r[p] = *(const short8*)(pB1 + (p << 9));
            }
            float4v a00 = zero4, a01 = zero4, a10 = zero4, a11 = zero4;
#pragma unroll
            for (int kt = 0; kt < 17; ++kt) {
                short8 aF0 = *(const short8*)&a_ga[(kt << 9) + lane * 8];
                short8 aF1 = *(const short8*)&a_ga[((24 + kt) << 9) + lane * 8];
                short8 bc0 = b0r[kt & 3];
                short8 bc1 = b1r[kt & 3];
                if (kt + 4 < 17) {
                    b0r[kt & 3] = *(const short8*)(pB0 + ((kt + 4) << 9));
                    b1r[kt & 3] = *(const short8*)(pB1 + ((kt + 4) << 9));
                }
                a00 = MFMA(aF0, bc0, a00); a01 = MFMA(aF0, bc1, a01);
                a10 = MFMA(aF1, bc0, a10); a11 = MFMA(aF1, bc1, a11);
            }
            // a3s write needs no pre-barrier (last read ≥2 barriers ago)
#pragma unroll
            for (int mt = 0; mt < 2; ++mt) {
                const float4v* am = (mt == 0) ? &a00 : &a10;
                const float4v* an = (mt == 0) ? &a01 : &a11;
#pragma unroll
                for (int i = 0; i < 4; ++i) {
                    int row = mt * 16 + quad * 4 + i;
                    {
                        int c = c10;
                        float hz = tanh_f((*am)[i] + bz0);
                        a3s[a3s_off(row, c & 255, c >> 8)] = f2bf(hz);
                    }
                    {
                        int c = c10 + 16;
                        float hz = tanh_f((*an)[i] + bz1);
                        a3s[a3s_off(row, c & 255, c >> 8)] = f2bf(hz);
                    }
                }
            }
            if (tid < BM) kl_acc[tid] = 0.f;
            __syncthreads();   // bar6
        }

        // ============ stage 4: mu/s heads, z_post, KL ============
        {
            const u16* pB0 = wts + W4_OFF + (((0 * 16 + wv) * 8) << 9) + lane * 8;
            const u16* pB1 = wts + W4_OFF + (((1 * 16 + wv) * 8) << 9) + lane * 8;
            const u16* pB2 = wts + W4_OFF + (((2 * 16 + wv) * 8) << 9) + lane * 8;
            const u16* pB3 = wts + W4_OFF + (((3 * 16 + wv) * 8) << 9) + lane * 8;
            short8 r0[2], r1[2], r2[2], r3[2];
#pragma unroll
            for (int p = 0; p < 2; ++p) {
                r0[p] = *(const short8*)(pB0 + (p << 9));
                r1[p] = *(const short8*)(pB1 + (p << 9));
                r2[p] = *(const short8*)(pB2 + (p << 9));
                r3[p] = *(const short8*)(pB3 + (p << 9));
            }
            float4v ac[4][2];
#pragma unroll
            for (int m = 0; m < 4; ++m) { ac[m][0] = zero4; ac[m][1] = zero4; }
#pragma unroll
            for (int kt = 0; kt < 8; ++kt) {
                short8 bm0 = r0[kt & 1], bm1 = r1[kt & 1];
                short8 bm2 = r2[kt & 1], bm3 = r3[kt & 1];
                if (kt + 2 < 8) {
                    r0[kt & 1] = *(const short8*)(pB0 + ((kt + 2) << 9));
                    r1[kt & 1] = *(const short8*)(pB1 + ((kt + 2) << 9));
                    r2[kt & 1] = *(const short8*)(pB2 + ((kt + 2) << 9));
                    r3[kt & 1] = *(const short8*)(pB3 + ((kt + 2) << 9));
                }
                short8 aP0 = *(const short8*)&a3s[((0 + kt) << 9) + lane * 8];          // P, mt0
                short8 aP1 = *(const short8*)&a3s[((8 + kt) << 9) + lane * 8];          // P, mt1
                short8 aQ0 = *(const short8*)&a3s[((16 + kt) << 9) + lane * 8];         // Q, mt0
                short8 aQ1 = *(const short8*)&a3s[((24 + kt) << 9) + lane * 8];         // Q, mt1
                ac[0][0] = MFMA(aP0, bm0, ac[0][0]); ac[0][1] = MFMA(aP1, bm0, ac[0][1]);
                ac[1][0] = MFMA(aP0, bm1, ac[1][0]); ac[1][1] = MFMA(aP1, bm1, ac[1][1]);
                ac[2][0] = MFMA(aQ0, bm2, ac[2][0]); ac[2][1] = MFMA(aQ1, bm2, ac[2][1]);
                ac[3][0] = MFMA(aQ0, bm3, ac[3][0]); ac[3][1] = MFMA(aQ1, bm3, ac[3][1]);
            }
            float kls[2][4];
#pragma unroll
            for (int mt = 0; mt < 2; ++mt)
#pragma unroll
                for (int i = 0; i < 4; ++i) {
                    int row = mt * 16 + quad * 4 + i;
                    float mu_p = ac[0][mt][i] + b4pm;
                    float s_p  = ac[1][mt][i] + b4ps;
                    float mu_q = ac[2][mt][i] + b4qm;
                    float s_q  = ac[3][mt][i] + b4qs;
                    float e = er[mt][i];
                    float zpost = mu_q + __expf(0.5f * s_q) * e;
                    float dmu = mu_q - mu_p;
                    kls[mt][i] = 0.5f * (s_p - s_q)
                               + (__expf(s_q) + dmu * dmu) * 0.5f * __expf(-s_p) - 0.5f;
                    a_ga[aga_off(row, 512 + zc)] = f2bf(zpost);
                }
#pragma unroll
            for (int mt = 0; mt < 2; ++mt)
#pragma unroll
                for (int i = 0; i < 4; ++i) {
                    float v = kls[mt][i];
                    v += __shfl_xor(v, 1); v += __shfl_xor(v, 2);
                    v += __shfl_xor(v, 4); v += __shfl_xor(v, 8);
                    if (l15 == 0) atomicAdd(&kl_acc[mt * 16 + quad * 4 + i], v);
                }
            __syncthreads();   // bar7
            if (tid < BM)
                __builtin_nontemporal_store(kl_acc[tid],
                    &out[YTOT + (size_t)(b0 + tid) * T_SZ + t]);
        }

        // ============ stage 5: g = tanh([x,h,z] @ Wg); y, g_T ============
        {
            const u16* pB = wts + WG_OFF + (((wv >> 1) * 24) << 9) + lane * 8;
            // prefetch next-t x while stage 5 computes (consumed at loop top)
            if (t + 1 < T_SZ) {
                const float* xp = &x[((size_t)(b0 + xr) * T_SZ + (t + 1)) * XD + xcc];
                xn0 = __builtin_nontemporal_load((const float4v*)xp);
                xn1 = __builtin_nontemporal_load((const float4v*)(xp + 4));
            }
            short8 wgr[4];
#pragma unroll
            for (int p = 0; p < 4; ++p)
                wgr[p] = *(const short8*)(pB + (p << 9));
            float4v a5 = zero4;
            const int abase = mt5 * 24;
#pragma unroll
            for (int kt = 0; kt < 24; ++kt) {
                short8 aF = *(const short8*)&a_ga[((abase + kt) << 9) + lane * 8];
                short8 bc = wgr[kt & 3];
                if (kt + 4 < 24)
                    wgr[kt & 3] = *(const short8*)(pB + ((kt + 4) << 9));
                a5 = MFMA(aF, bc, a5);
            }
            float g[4];
#pragma unroll
            for (int i = 0; i < 4; ++i) {
                int row = mt5 * 16 + quad * 4 + i;
                g[i] = tanh_f(a5[i] + bg_r);
                if (tph_s[row] - 1 == t)
                    __builtin_nontemporal_store(g[i],
                        &out[YTOT + KLTOT + (size_t)(b0 + row) * GD + c5]);
            }
#pragma unroll
            for (int i = 0; i < 4; ++i) {
                float p0 = g[i] * wy0, p1 = g[i] * wy1;
                p0 += __shfl_xor(p0, 1); p0 += __shfl_xor(p0, 2);
                p0 += __shfl_xor(p0, 4); p0 += __shfl_xor(p0, 8);
                p1 += __shfl_xor(p1, 1); p1 += __shfl_xor(p1, 2);
                p1 += __shfl_xor(p1, 4); p1 += __shfl_xor(p1, 8);
                if (l15 == 0) {
                    int row = mt5 * 16 + quad * 4 + i;
                    part[((wv >> 1) * BM + row) * 2]     = p0;
                    part[((wv >> 1) * BM + row) * 2 + 1] = p1;
                }
            }
            __syncthreads();   // bar8
            if (tid < BM) {
                int r = tid;
                float s0 = by0, s1 = by1;
#pragma unroll
                for (int j = 0; j < 8; ++j) {
                    s0 += part[(j * BM + r) * 2];
                    s1 += part[(j * BM + r) * 2 + 1];
                }
                float mx = fmaxf(s0, s1);
                float e0 = __expf(s0 - mx), e1 = __expf(s1 - mx);
                float inv = 1.f / (e0 + e1);
                size_t yoff = ((size_t)(b0 + r) * T_SZ + t) * YD;
                __builtin_nontemporal_store(e0 * inv, &out[yoff]);
                __builtin_nontemporal_store(e1 * inv, &out[yoff + 1]);
            }
        }
    }
}

extern "C" void kernel_launch(void* const* d_in, const int* in_sizes, int n_in,
                              void* d_out, int out_size, void* d_ws, size_t ws_size,
                              hipStream_t stream)
{
    const float* x   = (const float*)d_in[0];
    const float* yph = (const float*)d_in[1];
    const int*   Tph = (const int*)  d_in[2];
    const float* h0  = (const float*)d_in[3];
    const float* z0  = (const float*)d_in[4];
    const float* eps = (const float*)d_in[5];
    const float* Wr  = (const float*)d_in[6];
    const float* br  = (const float*)d_in[7];
    const float* Wu  = (const float*)d_in[8];
    const float* bu  = (const float*)d_in[9];
    const float* Wh  = (const float*)d_in[10];
    const float* bh  = (const float*)d_in[11];
    const float* Wzp = (const float*)d_in[12];
    const float* bzp = (const float*)d_in[13];
    const float* Wpm = (const float*)d_in[14];
    const float* bpm = (const float*)d_in[15];
    const float* Wps = (const float*)d_in[16];
    const float* bps = (const float*)d_in[17];
    const float* Wzq = (const float*)d_in[18];
    const float* bzq = (const float*)d_in[19];
    const float* Wqm = (const float*)d_in[20];
    const float* bqm = (const float*)d_in[21];
    const float* Wqs = (const float*)d_in[22];
    const float* bqs = (const float*)d_in[23];
    const float* Wg  = (const float*)d_in[24];
    const float* bg  = (const float*)d_in[25];
    const float* Wy  = (const float*)d_in[26];
    const float* by  = (const float*)d_in[27];
    u16*   wts = (u16*)d_ws;
    float* out = (float*)d_out;

    hipLaunchKernelGGL(prep_weights, dim3((WTOT + 255) / 256), dim3(256), 0, stream,
                       Wr, Wu, Wh, Wzp, Wzq, Wpm, Wps, Wqm, Wqs, Wg, wts);
    hipLaunchKernelGGL(vrnn_all, dim3(B_SZ / BM), dim3(1024), 0, stream,
                       x, yph, Tph, h0, z0, eps, br, bu, bh, bzp, bpm, bps,
                       bzq, bqm, bqs, bg, by, Wy, wts, out);
}

// Round 2
// 3976.184 us; speedup vs baseline: 1.2028x; 1.2028x over previous
//
#include <hip/hip_runtime.h>

typedef unsigned short u16;
typedef unsigned int u32;
typedef __attribute__((ext_vector_type(8))) short short8;
typedef __attribute__((ext_vector_type(4))) float float4v;
typedef __attribute__((ext_vector_type(2))) float float2v;

#define B_SZ 4096
#define T_SZ 32
#define XD 256
#define HD 256
#define ZD 256
#define GD 128
#define YD 2

#define BM 64          // batch rows per block
#define NW 16          // waves per block (1024 threads)

// bf16 weight fragment buffer layout in d_ws (elem offsets) — frag-contiguous:
// addr = base + ((ntile*KT + kt)<<9) + lane*8 + j ; lane=(n&15)|(((k>>3)&3)<<4), j=k&7
#define W1_OFF 0              // [Wr|Wu]  N=512 (32 ntiles), KT=24
#define W2_OFF 393216         // Wh       N=256 (16 ntiles), KT=24
#define W3_OFF 589824         // [Wzp|Wzq] N=512 (32 ntiles), KT=17 (K=544: x,h,y+pad; Wzp kt16 = zeros)
#define W4_OFF 868352         // [Wpm|Wps|Wqm|Wqs] N=1024 (64 ntiles), KT=8
#define WG_OFF 1130496        // Wg       N=128 (8 ntiles),  KT=24
#define WTOT   1228800

#define YTOT  (B_SZ*T_SZ*YD)        // 262144
#define KLTOT (B_SZ*T_SZ)           // 131072

#define UST 264    // u_bf row stride (bf16) inside a3u alias

__device__ __forceinline__ u16 f2bf(float f) {
    u32 u = __float_as_uint(f);
    u32 r = (u + 0x7fffu + ((u >> 16) & 1u)) >> 16;
    return (u16)r;
}
__device__ __forceinline__ float bf2f(u16 h) {
    return __uint_as_float(((u32)h) << 16);
}
__device__ __forceinline__ float tanh_f(float x) {
    float e = __expf(2.f * x);
    return 1.f - 2.f / (e + 1.f);
}
__device__ __forceinline__ float sigm_f(float x) {
    return 1.f / (1.f + __expf(-x));
}

// a_ga: 96 tiles ((r>>4)*24+kt) of 512 elems, frag-contiguous. rows 0..63, k 0..767
__device__ __forceinline__ int aga_off(int r, int k) {
    return (((r >> 4) * 24 + (k >> 5)) << 9) + ((((k >> 3) & 3) * 16 + (r & 15)) << 3) + (k & 7);
}
// a3s (P or Q, 64 x 256): 32 tiles ((r>>4)*8+kt)
__device__ __forceinline__ int a3_off(int r, int k) {
    return (((r >> 4) * 8 + (k >> 5)) << 9) + ((((k >> 3) & 3) * 16 + (r & 15)) << 3) + (k & 7);
}

#define MFMA(a, b, c) __builtin_amdgcn_mfma_f32_16x16x32_bf16(a, b, c, 0, 0, 0)

// ---------------------------------------------------------------------------
__global__ void prep_weights(const float* __restrict__ Wr, const float* __restrict__ Wu,
                             const float* __restrict__ Wh, const float* __restrict__ Wzp,
                             const float* __restrict__ Wzq, const float* __restrict__ Wpm,
                             const float* __restrict__ Wps, const float* __restrict__ Wqm,
                             const float* __restrict__ Wqs, const float* __restrict__ Wg,
                             u16* __restrict__ wts)
{
    int o = blockIdx.x * 256 + threadIdx.x;
    if (o >= WTOT) return;
    int mat, w, KT;
    if (o < W2_OFF)      { mat = 0; w = o;          KT = 24; }
    else if (o < W3_OFF) { mat = 1; w = o - W2_OFF; KT = 24; }
    else if (o < W4_OFF) { mat = 2; w = o - W3_OFF; KT = 17; }
    else if (o < WG_OFF) { mat = 3; w = o - W4_OFF; KT = 8;  }
    else                 { mat = 4; w = o - WG_OFF; KT = 24; }
    int nt  = w / (KT * 512);
    int rem = w - nt * (KT * 512);
    int kt  = rem >> 9;
    int q   = rem & 511;
    int lane = q >> 3, j = q & 7;
    int n = (nt << 4) | (lane & 15);
    int k = (kt << 5) + ((lane >> 4) << 3) + j;
    float v = 0.f;
    switch (mat) {
        case 0: v = (n < 256) ? Wr[k * 256 + n] : Wu[k * 256 + (n - 256)]; break;
        case 1: v = Wh[k * 256 + n]; break;
        case 2: v = (n < 256) ? (k < 512 ? Wzp[k * 256 + n] : 0.f)
                              : (k < 514 ? Wzq[k * 256 + (n - 256)] : 0.f); break;
        case 3: { int sel = n >> 8; int nn = n & 255;
                  const float* s = (sel == 0) ? Wpm : (sel == 1) ? Wps : (sel == 2) ? Wqm : Wqs;
                  v = s[k * 256 + nn]; } break;
        default: v = Wg[k * 128 + n]; break;
    }
    wts[o] = f2bf(v);
}

// ---------------------------------------------------------------------------
__global__ __launch_bounds__(1024, 4) void vrnn_all(
    const float* __restrict__ x,   const float* __restrict__ y_ph,
    const int*   __restrict__ Tph, const float* __restrict__ h0,
    const float* __restrict__ z0,  const float* __restrict__ eps,
    const float* __restrict__ br,  const float* __restrict__ bu,
    const float* __restrict__ bh,  const float* __restrict__ bzp,
    const float* __restrict__ bpm, const float* __restrict__ bps,
    const float* __restrict__ bzq, const float* __restrict__ bqm,
    const float* __restrict__ bqs, const float* __restrict__ bg,
    const float* __restrict__ by,  const float* __restrict__ Wy,
    const u16*   __restrict__ wts, float* __restrict__ out)
{
    __shared__ __align__(16) u16   a_ga[96 * 512];   // 98.3 KB  [x|h|z] frag tiles (64 rows)
    __shared__ __align__(16) u16   a3u[16896];       // 33.8 KB  union: P/Q frag (16384) | u_bf (64*264)
    __shared__ float part[8 * BM * 2];               // 4 KB  y-head partials
    __shared__ float kl_acc[BM];
    __shared__ int   tph_s[BM];

    const int tid  = threadIdx.x;
    const int wv   = tid >> 6;
    const int lane = tid & 63;
    const int quad = lane >> 4;
    const int l15  = lane & 15;
    const int b0   = blockIdx.x * BM;

    // --- per-lane register-resident biases / Wy ---
    const int c10 = wv * 32 + l15;          // stage1 cols (nt=0), +16 for nt=1
    const float bs1_0 = (c10 < 256) ? br[c10] : bu[c10 - 256];
    const float bs1_1 = (c10 + 16 < 256) ? br[c10 + 16] : bu[c10 + 16 - 256];
    const int c2  = wv * 16 + l15;          // stage2/3/4 col
    const float bh_r  = bh[c2];
    const float bzp_r = bzp[c2];
    const float bzq_r = bzq[c2];
    const float b4pm = bpm[c2], b4ps = bps[c2], b4qm = bqm[c2], b4qs = bqs[c2];
    const int c5  = (wv >> 1) * 16 + l15;   // stage5 col
    const int mt5 = wv & 1;
    const float bg_r = bg[c5];
    const float wy0 = Wy[c5 * 2], wy1 = Wy[c5 * 2 + 1];
    const float by0 = by[0], by1 = by[1];

    if (tid < BM) tph_s[tid] = Tph[b0 + tid];

    // --- fp32 recurrent h in registers (stage2 ownership: rows m*16+quad*4+i, col c2) ---
    float h32r[16];
#pragma unroll
    for (int m = 0; m < 4; ++m)
#pragma unroll
        for (int i = 0; i < 4; ++i) {
            int row = m * 16 + quad * 4 + i;
            h32r[m * 4 + i] = __builtin_nontemporal_load(&h0[(size_t)(b0 + row) * HD + c2]);
        }

    const int sr  = tid >> 4;          // staging row 0..63
    const int scc = (tid & 15) * 16;   // staging col base (16 cols per thread)

    // --- x(t=0) prefetch + bf16 h,z staging into a_ga ---
    float4v xn[4];
    {
        const float* xp = &x[((size_t)(b0 + sr) * T_SZ + 0) * XD + scc];
#pragma unroll
        for (int q = 0; q < 4; ++q) xn[q] = __builtin_nontemporal_load((const float4v*)(xp + q * 4));

        const float* hp = &h0[(size_t)(b0 + sr) * HD + scc];
        const float* zp = &z0[(size_t)(b0 + sr) * ZD + scc];
        float4v hv[4], zv[4];
#pragma unroll
        for (int q = 0; q < 4; ++q) {
            hv[q] = __builtin_nontemporal_load((const float4v*)(hp + q * 4));
            zv[q] = __builtin_nontemporal_load((const float4v*)(zp + q * 4));
        }
        short8 hs0, hs1, zs0, zs1;
#pragma unroll
        for (int j = 0; j < 4; ++j) {
            hs0[j] = (short)f2bf(hv[0][j]); hs0[4 + j] = (short)f2bf(hv[1][j]);
            hs1[j] = (short)f2bf(hv[2][j]); hs1[4 + j] = (short)f2bf(hv[3][j]);
            zs0[j] = (short)f2bf(zv[0][j]); zs0[4 + j] = (short)f2bf(zv[1][j]);
            zs1[j] = (short)f2bf(zv[2][j]); zs1[4 + j] = (short)f2bf(zv[3][j]);
        }
        *(short8*)&a_ga[aga_off(sr, 256 + scc)]     = hs0;
        *(short8*)&a_ga[aga_off(sr, 256 + scc + 8)] = hs1;
        *(short8*)&a_ga[aga_off(sr, 512 + scc)]     = zs0;
        *(short8*)&a_ga[aga_off(sr, 512 + scc + 8)] = zs1;
    }
    __syncthreads();

    const float4v zero4 = {0.f, 0.f, 0.f, 0.f};
    float yA0 = 0.f, yA1 = 0.f, yB0 = 0.f, yB1 = 0.f, klA = 0.f, klB = 0.f;

    for (int t = 0; t < T_SZ; ++t) {
        // --- stage x_t into a_ga cols [0,256) from prefetched registers ---
        {
            short8 s0, s1;
#pragma unroll
            for (int j = 0; j < 4; ++j) {
                s0[j] = (short)f2bf(xn[0][j]); s0[4 + j] = (short)f2bf(xn[1][j]);
                s1[j] = (short)f2bf(xn[2][j]); s1[4 + j] = (short)f2bf(xn[3][j]);
            }
            *(short8*)&a_ga[aga_off(sr, scc)]     = s0;
            *(short8*)&a_ga[aga_off(sr, scc + 8)] = s1;
        }
        __syncthreads();   // bar1

        // ============ stage 1: [r|u] = sigmoid([x,h,z] @ W1) ============
        {
            const u16* pB0 = wts + W1_OFF + (((2 * wv    ) * 24) << 9) + lane * 8;
            const u16* pB1 = wts + W1_OFF + (((2 * wv + 1) * 24) << 9) + lane * 8;
            short8 r0[2], r1[2];
            r0[0] = *(const short8*)pB0;         r1[0] = *(const short8*)pB1;
            r0[1] = *(const short8*)(pB0 + 512); r1[1] = *(const short8*)(pB1 + 512);
            float4v a0[4], a1[4];
#pragma unroll
            for (int m = 0; m < 4; ++m) { a0[m] = zero4; a1[m] = zero4; }
#pragma unroll
            for (int kt = 0; kt < 24; ++kt) {
                short8 bc0 = r0[kt & 1], bc1 = r1[kt & 1];
                if (kt + 2 < 24) {
                    r0[kt & 1] = *(const short8*)(pB0 + ((kt + 2) << 9));
                    r1[kt & 1] = *(const short8*)(pB1 + ((kt + 2) << 9));
                }
#pragma unroll
                for (int m = 0; m < 4; ++m) {
                    short8 aF = *(const short8*)&a_ga[((m * 24 + kt) << 9) + lane * 8];
                    a0[m] = MFMA(aF, bc0, a0[m]);
                    a1[m] = MFMA(aF, bc1, a1[m]);
                }
            }
            __syncthreads();   // bar2: all a_ga reads done before rh overwrite
#pragma unroll
            for (int m = 0; m < 4; ++m)
#pragma unroll
                for (int i = 0; i < 4; ++i) {
                    int row = m * 16 + quad * 4 + i;
                    {
                        float v = a0[m][i];
                        if (c10 < 256) {
                            int o = aga_off(row, 256 + c10);
                            float rr = sigm_f(v + bs1_0);
                            a_ga[o] = f2bf(rr * bf2f(a_ga[o]));
                        } else {
                            a3u[row * UST + (c10 - 256)] = f2bf(sigm_f(v + bs1_0));
                        }
                    }
                    {
                        int c = c10 + 16;
                        float v = a1[m][i];
                        if (c < 256) {
                            int o = aga_off(row, 256 + c);
                            float rr = sigm_f(v + bs1_1);
                            a_ga[o] = f2bf(rr * bf2f(a_ga[o]));
                        } else {
                            a3u[row * UST + (c - 256)] = f2bf(sigm_f(v + bs1_1));
                        }
                    }
                }
            __syncthreads();   // bar3
        }

        // ============ stage 2: h_tilde = tanh([x,rh,z] @ Wh); h update ============
        {
            const u16* pB = wts + W2_OFF + ((wv * 24) << 9) + lane * 8;
            short8 rr2[2];
            rr2[0] = *(const short8*)pB; rr2[1] = *(const short8*)(pB + 512);
            float4v a[4];
#pragma unroll
            for (int m = 0; m < 4; ++m) a[m] = zero4;
#pragma unroll
            for (int kt = 0; kt < 24; ++kt) {
                short8 bc = rr2[kt & 1];
                if (kt + 2 < 24) rr2[kt & 1] = *(const short8*)(pB + ((kt + 2) << 9));
#pragma unroll
                for (int m = 0; m < 4; ++m) {
                    short8 aF = *(const short8*)&a_ga[((m * 24 + kt) << 9) + lane * 8];
                    a[m] = MFMA(aF, bc, a[m]);
                }
            }
            __syncthreads();   // bar4: a_ga reads done before h / y writes
#pragma unroll
            for (int m = 0; m < 4; ++m)
#pragma unroll
                for (int i = 0; i < 4; ++i) {
                    int row = m * 16 + quad * 4 + i;
                    float ht = tanh_f(a[m][i] + bh_r);
                    float uu = bf2f(a3u[row * UST + c2]);
                    float h  = (1.f - uu) * h32r[m * 4 + i] + uu * ht;
                    h32r[m * 4 + i] = h;
                    a_ga[aga_off(row, 256 + c2)] = f2bf(h);
                }
            // y_t + zeros into cols [512,544) (tile kt=16)
            if (tid < 256) {
                int r = tid >> 2, grp = tid & 3;
                short8 v = {0, 0, 0, 0, 0, 0, 0, 0};
                if (grp == 0) {
                    const float* yp = &y_ph[((size_t)(b0 + r) * T_SZ + t) * YD];
                    v[0] = (short)f2bf(__builtin_nontemporal_load(yp));
                    v[1] = (short)f2bf(__builtin_nontemporal_load(yp + 1));
                }
                *(short8*)&a_ga[aga_off(r, 512 + grp * 8)] = v;
            }
            __syncthreads();   // bar5
        }

        // ============ stage 3a: hzp = tanh([x,h] @ Wzp) -> a3u(P) ============
        {
            const u16* pB = wts + W3_OFF + ((wv * 17) << 9) + lane * 8;
            short8 r3[2];
            r3[0] = *(const short8*)pB; r3[1] = *(const short8*)(pB + 512);
            float4v a[4];
#pragma unroll
            for (int m = 0; m < 4; ++m) a[m] = zero4;
#pragma unroll
            for (int kt = 0; kt < 16; ++kt) {     // Wzp K=512 (skip zero kt=16)
                short8 bc = r3[kt & 1];
                if (kt + 2 < 16) r3[kt & 1] = *(const short8*)(pB + ((kt + 2) << 9));
#pragma unroll
                for (int m = 0; m < 4; ++m) {
                    short8 aF = *(const short8*)&a_ga[((m * 24 + kt) << 9) + lane * 8];
                    a[m] = MFMA(aF, bc, a[m]);
                }
            }
            // write P (u_bf dead since bar5; a3s last read ≥2 barriers ago)
#pragma unroll
            for (int m = 0; m < 4; ++m)
#pragma unroll
                for (int i = 0; i < 4; ++i) {
                    int row = m * 16 + quad * 4 + i;
                    a3u[a3_off(row, c2)] = f2bf(tanh_f(a[m][i] + bzp_r));
                }
            __syncthreads();   // bar6a
        }

        // ============ stage 4a: mu_p/s_p = hzp @ [Wpm|Wps] -> regs ============
        float mu_p[16], s_p[16];
        {
            const u16* pBm = wts + W4_OFF + ((wv * 8) << 9) + lane * 8;
            const u16* pBs = wts + W4_OFF + (((16 + wv) * 8) << 9) + lane * 8;
            short8 rm[2], rs[2];
            rm[0] = *(const short8*)pBm;         rs[0] = *(const short8*)pBs;
            rm[1] = *(const short8*)(pBm + 512); rs[1] = *(const short8*)(pBs + 512);
            float4v am[4], as4[4];
#pragma unroll
            for (int m = 0; m < 4; ++m) { am[m] = zero4; as4[m] = zero4; }
#pragma unroll
            for (int kt = 0; kt < 8; ++kt) {
                short8 bm = rm[kt & 1], bs = rs[kt & 1];
                if (kt + 2 < 8) {
                    rm[kt & 1] = *(const short8*)(pBm + ((kt + 2) << 9));
                    rs[kt & 1] = *(const short8*)(pBs + ((kt + 2) << 9));
                }
#pragma unroll
                for (int m = 0; m < 4; ++m) {
                    short8 aF = *(const short8*)&a3u[((m * 8 + kt) << 9) + lane * 8];
                    am[m]  = MFMA(aF, bm, am[m]);
                    as4[m] = MFMA(aF, bs, as4[m]);
                }
            }
#pragma unroll
            for (int m = 0; m < 4; ++m)
#pragma unroll
                for (int i = 0; i < 4; ++i) {
                    mu_p[m * 4 + i] = am[m][i]  + b4pm;
                    s_p[m * 4 + i]  = as4[m][i] + b4ps;
                }
        }

        // ============ stage 3b: hzq = tanh([x,h,y] @ Wzq) -> a3u(Q) ============
        float er[16];
        {
            // eps prefetch (consumed in stage 4b epilogue; latency hidden by 17-kt loop)
#pragma unroll
            for (int m = 0; m < 4; ++m)
#pragma unroll
                for (int i = 0; i < 4; ++i) {
                    int row = m * 16 + quad * 4 + i;
                    er[m * 4 + i] = __builtin_nontemporal_load(
                        &eps[((size_t)t * B_SZ + (b0 + row)) * ZD + c2]);
                }
            const u16* pB = wts + W3_OFF + (((16 + wv) * 17) << 9) + lane * 8;
            short8 r3[2];
            r3[0] = *(const short8*)pB; r3[1] = *(const short8*)(pB + 512);
            float4v a[4];
#pragma unroll
            for (int m = 0; m < 4; ++m) a[m] = zero4;
#pragma unroll
            for (int kt = 0; kt < 17; ++kt) {
                short8 bc = r3[kt & 1];
                if (kt + 2 < 17) r3[kt & 1] = *(const short8*)(pB + ((kt + 2) << 9));
#pragma unroll
                for (int m = 0; m < 4; ++m) {
                    short8 aF = *(const short8*)&a_ga[((m * 24 + kt) << 9) + lane * 8];
                    a[m] = MFMA(aF, bc, a[m]);
                }
            }
            if (tid < BM) kl_acc[tid] = 0.f;
            __syncthreads();   // bar6b: all stage-4a P reads complete before Q overwrite
#pragma unroll
            for (int m = 0; m < 4; ++m)
#pragma unroll
                for (int i = 0; i < 4; ++i) {
                    int row = m * 16 + quad * 4 + i;
                    a3u[a3_off(row, c2)] = f2bf(tanh_f(a[m][i] + bzq_r));
                }
            __syncthreads();   // bar6c
        }

        // ============ stage 4b: mu_q/s_q heads, z_post, KL ============
        {
            const u16* pBm = wts + W4_OFF + (((32 + wv) * 8) << 9) + lane * 8;
            const u16* pBs = wts + W4_OFF + (((48 + wv) * 8) << 9) + lane * 8;
            short8 rm[2], rs[2];
            rm[0] = *(const short8*)pBm;         rs[0] = *(const short8*)pBs;
            rm[1] = *(const short8*)(pBm + 512); rs[1] = *(const short8*)(pBs + 512);
            float4v am[4], as4[4];
#pragma unroll
            for (int m = 0; m < 4; ++m) { am[m] = zero4; as4[m] = zero4; }
#pragma unroll
            for (int kt = 0; kt < 8; ++kt) {
                short8 bm = rm[kt & 1], bs = rs[kt & 1];
                if (kt + 2 < 8) {
                    rm[kt & 1] = *(const short8*)(pBm + ((kt + 2) << 9));
                    rs[kt & 1] = *(const short8*)(pBs + ((kt + 2) << 9));
                }
#pragma unroll
                for (int m = 0; m < 4; ++m) {
                    short8 aF = *(const short8*)&a3u[((m * 8 + kt) << 9) + lane * 8];
                    am[m]  = MFMA(aF, bm, am[m]);
                    as4[m] = MFMA(aF, bs, as4[m]);
                }
            }
            float kls[16];
#pragma unroll
            for (int m = 0; m < 4; ++m)
#pragma unroll
                for (int i = 0; i < 4; ++i) {
                    int row = m * 16 + quad * 4 + i;
                    float mq = am[m][i]  + b4qm;
                    float sq = as4[m][i] + b4qs;
                    float mp = mu_p[m * 4 + i], sp = s_p[m * 4 + i];
                    float zpost = mq + __expf(0.5f * sq) * er[m * 4 + i];
                    float dmu = mq - mp;
                    kls[m * 4 + i] = 0.5f * (sp - sq)
                                   + (__expf(sq) + dmu * dmu) * 0.5f * __expf(-sp) - 0.5f;
                    a_ga[aga_off(row, 512 + c2)] = f2bf(zpost);
                }
#pragma unroll
            for (int m = 0; m < 4; ++m)
#pragma unroll
                for (int i = 0; i < 4; ++i) {
                    float v = kls[m * 4 + i];
                    v += __shfl_xor(v, 1); v += __shfl_xor(v, 2);
                    v += __shfl_xor(v, 4); v += __shfl_xor(v, 8);
                    if (l15 == 0) atomicAdd(&kl_acc[m * 16 + quad * 4 + i], v);
                }
            __syncthreads();   // bar7
            if ((tid & 15) == (t >> 1)) {
                float k = kl_acc[tid >> 4];
                if ((t & 1) == 0) klA = k; else klB = k;
            }
        }

        // ============ stage 5: g = tanh([x,h,z] @ Wg); y, g_T ============
        {
            // prefetch next-t x while stage 5 computes (consumed at loop top)
            if (t + 1 < T_SZ) {
                const float* xp = &x[((size_t)(b0 + sr) * T_SZ + (t + 1)) * XD + scc];
#pragma unroll
                for (int q = 0; q < 4; ++q)
                    xn[q] = __builtin_nontemporal_load((const float4v*)(xp + q * 4));
            }
            const u16* pB = wts + WG_OFF + (((wv >> 1) * 24) << 9) + lane * 8;
            short8 rg[2];
            rg[0] = *(const short8*)pB; rg[1] = *(const short8*)(pB + 512);
            float4v a5[2];
            a5[0] = zero4; a5[1] = zero4;
#pragma unroll
            for (int kt = 0; kt < 24; ++kt) {
                short8 bc = rg[kt & 1];
                if (kt + 2 < 24) rg[kt & 1] = *(const short8*)(pB + ((kt + 2) << 9));
                short8 aFa = *(const short8*)&a_ga[(((mt5    ) * 24 + kt) << 9) + lane * 8];
                short8 aFb = *(const short8*)&a_ga[(((mt5 + 2) * 24 + kt) << 9) + lane * 8];
                a5[0] = MFMA(aFa, bc, a5[0]);
                a5[1] = MFMA(aFb, bc, a5[1]);
            }
#pragma unroll
            for (int half = 0; half < 2; ++half) {
                int m = mt5 + 2 * half;
#pragma unroll
                for (int i = 0; i < 4; ++i) {
                    int row = m * 16 + quad * 4 + i;
                    float g = tanh_f(a5[half][i] + bg_r);
                    if (tph_s[row] - 1 == t)
                        __builtin_nontemporal_store(g,
                            &out[YTOT + KLTOT + (size_t)(b0 + row) * GD + c5]);
                    float p0 = g * wy0, p1 = g * wy1;
                    p0 += __shfl_xor(p0, 1); p0 += __shfl_xor(p0, 2);
                    p0 += __shfl_xor(p0, 4); p0 += __shfl_xor(p0, 8);
                    p1 += __shfl_xor(p1, 1); p1 += __shfl_xor(p1, 2);
                    p1 += __shfl_xor(p1, 4); p1 += __shfl_xor(p1, 8);
                    if (l15 == 0) {
                        part[((wv >> 1) * BM + row) * 2]     = p0;
                        part[((wv >> 1) * BM + row) * 2 + 1] = p1;
                    }
                }
            }
            __syncthreads();   // bar8
            if ((tid & 15) == (t >> 1)) {
                int r = tid >> 4;
                float s0 = by0, s1 = by1;
#pragma unroll
                for (int j = 0; j < 8; ++j) {
                    s0 += part[(j * BM + r) * 2];
                    s1 += part[(j * BM + r) * 2 + 1];
                }
                float mx = fmaxf(s0, s1);
                float e0 = __expf(s0 - mx), e1 = __expf(s1 - mx);
                float inv = 1.f / (e0 + e1);
                if ((t & 1) == 0) { yA0 = e0 * inv; yA1 = e1 * inv; }
                else              { yB0 = e0 * inv; yB1 = e1 * inv; }
            }
        }
    }

    // --- final coalesced flush of y and kl (owner thread tid = r*16 + t/2) ---
    {
        int r = tid >> 4, tt = tid & 15;
        float4v yv = {yA0, yA1, yB0, yB1};
        __builtin_nontemporal_store(yv,
            (float4v*)&out[((size_t)(b0 + r) * T_SZ + tt * 2) * YD]);
        float2v kv = {klA, klB};
        __builtin_nontemporal_store(kv,
            (float2v*)&out[YTOT + (size_t)(b0 + r) * T_SZ + tt * 2]);
    }
}

extern "C" void kernel_launch(void* const* d_in, const int* in_sizes, int n_in,
                              void* d_out, int out_size, void* d_ws, size_t ws_size,
                              hipStream_t stream)
{
    const float* x   = (const float*)d_in[0];
    const float* yph = (const float*)d_in[1];
    const int*   Tph = (const int*)  d_in[2];
    const float* h0  = (const float*)d_in[3];
    const float* z0  = (const float*)d_in[4];
    const float* eps = (const float*)d_in[5];
    const float* Wr  = (const float*)d_in[6];
    const float* br  = (const float*)d_in[7];
    const float* Wu  = (const float*)d_in[8];
    const float* bu  = (const float*)d_in[9];
    const float* Wh  = (const float*)d_in[10];
    const float* bh  = (const float*)d_in[11];
    const float* Wzp = (const float*)d_in[12];
    const float* bzp = (const float*)d_in[13];
    const float* Wpm = (const float*)d_in[14];
    const float* bpm = (const float*)d_in[15];
    const float* Wps = (const float*)d_in[16];
    const float* bps = (const float*)d_in[17];
    const float* Wzq = (const float*)d_in[18];
    const float* bzq = (const float*)d_in[19];
    const float* Wqm = (const float*)d_in[20];
    const float* bqm = (const float*)d_in[21];
    const float* Wqs = (const float*)d_in[22];
    const float* bqs = (const float*)d_in[23];
    const float* Wg  = (const float*)d_in[24];
    const float* bg  = (const float*)d_in[25];
    const float* Wy  = (const float*)d_in[26];
    const float* by  = (const float*)d_in[27];
    u16*   wts = (u16*)d_ws;
    float* out = (float*)d_out;

    hipLaunchKernelGGL(prep_weights, dim3((WTOT + 255) / 256), dim3(256), 0, stream,
                       Wr, Wu, Wh, Wzp, Wzq, Wpm, Wps, Wqm, Wqs, Wg, wts);
    hipLaunchKernelGGL(vrnn_all, dim3(B_SZ / BM), dim3(1024), 0, stream,
                       x, yph, Tph, h0, z0, eps, br, bu, bh, bzp, bpm, bps,
                       bzq, bqm, bqs, bg, by, Wy, wts, out);
}